// Round 7
// baseline (1888.084 us; speedup 1.0000x reference)
//
#include <hip/hip_runtime.h>
#include <stdint.h>
#include <stddef.h>

// ---------------------------------------------------------------------------
// Controller (LSTM policy sampler) — round 6.
// Round-5 probe proved: output layout correct, step-0 actions decorrelated
// -> RNG machinery bug. Fix: JAX >= 0.4.30 defaults jax_threefry_partitionable
// = True, so random_bits is the PARTITIONABLE stream:
//   bits[e] = out0 ^ out1 of threefry2x32(key, (hi32(e), lo32(e)))   [32-bit]
// (legacy iota-halves mapping removed). fold_in unchanged by the flag.
// All continuous math in f64; exact-order reductions; f32 in / f32 out.
// ---------------------------------------------------------------------------

#define NOPS 14
#define NMAGS 10
#define QC 5
#define NSTEP 8
#define TOT 40
#define EMB 32
#define HID 100
#define KR 132            // EMB + HID
#define BTOT 8192
#define ROWS 32
#define NT 512
#define NBLK (BTOT / ROWS)   // 256

#define WQ_QUADS (KR * 128)              // 16896 float4 quads
#define ACC_BYTE_OFF (WQ_QUADS * 16)     // 270336 bytes

// d_out layout (f32 elements, concatenated reference outputs)
#define OUT_OPM  (BTOT * TOT)            // 327680
#define OUT_MAGM (OUT_OPM + NOPS)        // 327694
#define OUT_LPS  (OUT_MAGM + NMAGS)      // 327704
#define OUT_ENTS (OUT_LPS + BTOT)        // 335896

struct KeyArr { uint32_t k[TOT * 2]; };

// ---- threefry2x32-20 (Random123 / jax._src.prng) --------------------------
__host__ __device__ inline void tf2x32(uint32_t k0, uint32_t k1,
                                       uint32_t x0, uint32_t x1,
                                       uint32_t& o0, uint32_t& o1) {
  uint32_t k2 = k0 ^ k1 ^ 0x1BD11BDAu;
#define TFR(r) { x0 += x1; x1 = (x1 << (r)) | (x1 >> (32 - (r))); x1 ^= x0; }
  x0 += k0; x1 += k1;
  TFR(13) TFR(15) TFR(26) TFR(6)
  x0 += k1; x1 += k2 + 1u;
  TFR(17) TFR(29) TFR(16) TFR(24)
  x0 += k2; x1 += k0 + 2u;
  TFR(13) TFR(15) TFR(26) TFR(6)
  x0 += k0; x1 += k1 + 3u;
  TFR(17) TFR(29) TFR(16) TFR(24)
  x0 += k1; x1 += k2 + 4u;
  TFR(13) TFR(15) TFR(26) TFR(6)
  x0 += k2; x1 += k0 + 5u;
#undef TFR
  o0 = x0; o1 = x1;
}

// ---- gumbel, partitionable-threefry bits, f64 downstream ------------------
// partitionable random_bits(32): count e -> threefry(key, (0, e)), bits =
// out0 ^ out1. uniform: u = bitcast(bits>>9 | 0x3f800000) - 1 (exact f32);
// *(1-tiny)+tiny == identity except u==0 -> tiny; max(tiny, .).
// gumbel = -log(-log(u)), evaluated in f64.
__device__ __forceinline__ double gumbel64(uint32_t key0, uint32_t key1,
                                           uint32_t e) {
  uint32_t o0, o1;
  tf2x32(key0, key1, 0u, e, o0, o1);
  uint32_t bits = o0 ^ o1;
  float uf = __uint_as_float((bits >> 9) | 0x3f800000u) - 1.0f;  // exact
  double u = (double)uf;
  if (u == 0.0) u = 1.1754943508222875e-38;  // f32 tiny
  return -log(-log(u));
}

__device__ __forceinline__ double sigmoid64(double x) {
  return 1.0 / (1.0 + exp(-x));
}

// ---- prep: W_ih/W_hh -> quad layout ws[k][j] = {i,f,g,o}[j] at input k ----
__global__ void ctrl_prep(const float* __restrict__ W_ih,
                          const float* __restrict__ W_hh,
                          float* __restrict__ wsf, double* __restrict__ gacc) {
  int gid = blockIdx.x * blockDim.x + threadIdx.x;
  if (gid < WQ_QUADS) {
    int k = gid >> 7, j = gid & 127;
    float4 v = {0.f, 0.f, 0.f, 0.f};
    if (j < HID) {
      float* vf = &v.x;
#pragma unroll
      for (int g = 0; g < 4; ++g) {
        int row = g * HID + j;            // torch gate order i,f,g,o
        vf[g] = (k < EMB) ? W_ih[row * EMB + k] : W_hh[row * HID + (k - EMB)];
      }
    }
    ((float4*)wsf)[gid] = v;
  }
  if (gid < NOPS + NMAGS) gacc[gid] = 0.0;
}

// ---- main -----------------------------------------------------------------
__global__ __launch_bounds__(NT)
void ctrl_main(const float* __restrict__ emb,
               const float* __restrict__ b_ih, const float* __restrict__ b_hh,
               const float* __restrict__ W_op, const float* __restrict__ b_op,
               const float* __restrict__ W_mag, const float* __restrict__ b_mag,
               const float* __restrict__ wsf, double* __restrict__ gacc,
               float* __restrict__ out, KeyArr keys) {
  __shared__ double xh[KR][ROWS];        // rows of [x(32); h(100)], k-major
  __shared__ double zb[ROWS][16], gb[ROWS][16], pb[ROWS][16];
  __shared__ double lpacc[ROWS], enacc[ROWS];
  __shared__ double opL[NOPS], magL[NMAGS];
  __shared__ int act[ROWS];

  const int tid = threadIdx.x;
  const int jq = tid & 127;              // gate-unit column (0..99 active)
  const int rb = (tid >> 7) * 8;         // row quarter base
  const int base_b = blockIdx.x * ROWS;
  const bool unit_on = (jq < HID);

  if (tid < ROWS) { lpacc[tid] = 0.0; enacc[tid] = 0.0; }
  if (tid < NOPS) opL[tid] = 0.0;
  if (tid >= 32 && tid < 32 + NMAGS) magL[tid - 32] = 0.0;

  const float4* Wq = (const float4*)wsf;

  double bsi = 0, bsf = 0, bsg = 0, bso = 0;
  if (unit_on) {
    bsi = (double)b_ih[jq]       + (double)b_hh[jq];
    bsf = (double)b_ih[100 + jq] + (double)b_hh[100 + jq];
    bsg = (double)b_ih[200 + jq] + (double)b_hh[200 + jq];
    bso = (double)b_ih[300 + jq] + (double)b_hh[300 + jq];
  }

  for (int q = 0; q < QC; ++q) {
    // chain reset: x = 0, h = 0, c = 0
    for (int t = tid; t < KR * ROWS; t += NT) (&xh[0][0])[t] = 0.0;
    double creg[8];
#pragma unroll
    for (int r = 0; r < 8; ++r) creg[r] = 0.0;
    __syncthreads();

    for (int js = 0; js < NSTEP; ++js) {
      // ---- gates = [x;h] . Wq  (k-sequential f64 fma, 8 rows/thread) ----
      double ai[8], af[8], ag[8], ao[8];
#pragma unroll
      for (int r = 0; r < 8; ++r) { ai[r] = af[r] = ag[r] = ao[r] = 0.0; }
      for (int k = 0; k < KR; ++k) {
        float4 w = Wq[k * 128 + jq];
        double wi = (double)w.x, wf = (double)w.y;
        double wg = (double)w.z, wo = (double)w.w;
#pragma unroll
        for (int r = 0; r < 8; ++r) {
          double xv = xh[k][rb + r];
          ai[r] = fma(wi, xv, ai[r]);
          af[r] = fma(wf, xv, af[r]);
          ag[r] = fma(wg, xv, ag[r]);
          ao[r] = fma(wo, xv, ao[r]);
        }
      }
      double h2[8];
      if (unit_on) {
#pragma unroll
        for (int r = 0; r < 8; ++r) {
          double c2 = sigmoid64(af[r] + bsf) * creg[r] +
                      sigmoid64(ai[r] + bsi) * tanh(ag[r] + bsg);
          creg[r] = c2;
          h2[r] = sigmoid64(ao[r] + bso) * tanh(c2);
        }
      }
      __syncthreads();                   // old xh fully consumed
      if (unit_on) {
#pragma unroll
        for (int r = 0; r < 8; ++r) xh[EMB + jq][rb + r] = h2[r];
      }
      __syncthreads();                   // new h visible

      // ---- head logits -> z, gumbel ----
      const int sidx = q * NSTEP + js;
      const uint32_t key0 = keys.k[2 * sidx], key1 = keys.k[2 * sidx + 1];
      const int K = (js & 1) ? NMAGS : NOPS;
      const float* Wh = (js & 1) ? W_mag : W_op;
      const float* bh = (js & 1) ? b_mag : b_op;
      if (tid < ROWS * K) {
        int r = tid / K, c = tid - r * K;
        const float* wrow = Wh + c * HID;
        double acc = 0.0;
        for (int k = 0; k < HID; ++k)
          acc = fma((double)wrow[k], xh[EMB + k][r], acc);
        zb[r][c] = 2.5 * tanh(acc + (double)bh[c]);  // C*tanh/T, T=1
        gb[r][c] = gumbel64(key0, key1, (uint32_t)((base_b + r) * K + c));
      }
      __syncthreads();

      // ---- per-row softmax / entropy / gumbel-argmax (serial, f64) ----
      if (tid < ROWS) {
        const int r = tid;
        double m = zb[r][0];
        for (int k = 1; k < K; ++k) m = fmax(m, zb[r][k]);
        double s = 0.0;
        for (int k = 0; k < K; ++k) s += exp(zb[r][k] - m);
        double ls = log(s);
        double ent = 0.0, best = 0.0, sel = 0.0;
        int bi = 0;
        for (int k = 0; k < K; ++k) {
          double zk = zb[r][k];
          double lp = zk - m - ls;
          double pr = exp(lp);
          pb[r][k] = pr;
          ent += lp * pr;
          double sc = gb[r][k] + zk;     // argmax(z + gumbel), first-max tie
          if (k == 0 || sc > best) { best = sc; bi = k; sel = lp; }
        }
        out[(size_t)(base_b + r) * TOT + sidx] = (float)bi;
        lpacc[r] += sel;                 // exact order: q asc, js asc
        enacc[r] += -ent;
        act[r] = bi + ((js & 1) ? NOPS : 0);
      }
      __syncthreads();

      // ---- class prob sums; next x = embedding[act] ----
      if (tid < K) {
        double cs = 0.0;
        for (int r = 0; r < ROWS; ++r) cs += pb[r][tid];
        if (js & 1) magL[tid] += cs; else opL[tid] += cs;
      }
      if (js < NSTEP - 1) {
        for (int t = tid; t < ROWS * EMB; t += NT) {
          int r = t & 31, e = t >> 5;
          xh[e][r] = (double)emb[act[r] * EMB + e];
        }
      }
      __syncthreads();
    }
  }

  if (tid < ROWS) {
    out[OUT_LPS + base_b + tid]  = (float)lpacc[tid];
    out[OUT_ENTS + base_b + tid] = (float)enacc[tid];
  }
  if (tid < NOPS) atomicAdd(&gacc[tid], opL[tid]);
  if (tid >= 32 && tid < 32 + NMAGS)
    atomicAdd(&gacc[NOPS + (tid - 32)], magL[tid - 32]);
}

// ---- finish: prob means -> out --------------------------------------------
__global__ void ctrl_fin(const double* __restrict__ gacc,
                         float* __restrict__ out) {
  int t = threadIdx.x;
  if (t < NOPS) out[OUT_OPM + t] = (float)(gacc[t] / 163840.0);
  else if (t < NOPS + NMAGS)
    out[OUT_MAGM + (t - NOPS)] = (float)(gacc[t] / 163840.0);
}

extern "C" void kernel_launch(void* const* d_in, const int* in_sizes, int n_in,
                              void* d_out, int out_size, void* d_ws,
                              size_t ws_size, hipStream_t stream) {
  const float* emb   = (const float*)d_in[0];
  const float* W_ih  = (const float*)d_in[1];
  const float* W_hh  = (const float*)d_in[2];
  const float* b_ih  = (const float*)d_in[3];
  const float* b_hh  = (const float*)d_in[4];
  const float* W_op  = (const float*)d_in[5];
  const float* b_op  = (const float*)d_in[6];
  const float* W_mag = (const float*)d_in[7];
  const float* b_mag = (const float*)d_in[8];
  float* out = (float*)d_out;
  float* wsf = (float*)d_ws;
  double* gacc = (double*)((char*)d_ws + ACC_BYTE_OFF);

  // fold_in(key(42), s) = threefry2x32(key=(0,42), count=(0,s))
  // (fold_in is NOT affected by jax_threefry_partitionable)
  KeyArr keys;
  for (int s = 0; s < TOT; ++s) {
    uint32_t o0, o1;
    tf2x32(0u, 42u, 0u, (uint32_t)s, o0, o1);
    keys.k[2 * s] = o0;
    keys.k[2 * s + 1] = o1;
  }

  ctrl_prep<<<dim3((WQ_QUADS + 255) / 256), dim3(256), 0, stream>>>(
      W_ih, W_hh, wsf, gacc);
  ctrl_main<<<dim3(NBLK), dim3(NT), 0, stream>>>(
      emb, b_ih, b_hh, W_op, b_op, W_mag, b_mag, wsf, gacc, out, keys);
  ctrl_fin<<<dim3(1), dim3(64), 0, stream>>>(gacc, out);
}

// Round 8
// 1187.172 us; speedup vs baseline: 1.5904x; 1.5904x over previous
//
#include <hip/hip_runtime.h>
#include <stdint.h>
#include <stddef.h>

// ---------------------------------------------------------------------------
// Controller (LSTM policy sampler) — round 7 (perf round; r6 PASSED absmax 0.0).
// Structure: 1280 blocks (5 q-chains x 256 row-groups) x 448 threads.
//  - PX table: x@W_ih^T precomputed for all 25 possible inputs -> k-loop 100.
//  - h double-buffered in LDS, 3 barriers/step.
//  - custom f64 exp/log (<=1e-15 rel; established slack is ~1e-6 margins).
//  - per-q lp/ent partials, summed in q order by fin kernel.
// ---------------------------------------------------------------------------

#define NOPS 14
#define NMAGS 10
#define QC 5
#define NSTEP 8
#define TOT 40
#define EMB 32
#define HID 100
#define BTOT 8192
#define ROWS 32
#define NT 448
#define NCOL 112
#define NBLK 1280

// ws layout (doubles)
#define WHH_D  0
#define WHH_ND (HID * NCOL * 4)            // 44800
#define PX_D   WHH_ND
#define PX_ND  (25 * NCOL * 4)             // 11200
#define LPP_D  (PX_D + PX_ND)              // 56000
#define ENP_D  (LPP_D + QC * BTOT)         // 96960
#define GACC_D (ENP_D + QC * BTOT)         // 137920

// d_out layout (f32)
#define OUT_OPM  (BTOT * TOT)              // 327680
#define OUT_MAGM (OUT_OPM + NOPS)          // 327694
#define OUT_LPS  (OUT_MAGM + NMAGS)        // 327704
#define OUT_ENTS (OUT_LPS + BTOT)          // 335896

struct KeyArr { uint32_t k[TOT * 2]; };

// ---- threefry2x32-20 (jax._src.prng) --------------------------------------
__host__ __device__ inline void tf2x32(uint32_t k0, uint32_t k1,
                                       uint32_t x0, uint32_t x1,
                                       uint32_t& o0, uint32_t& o1) {
  uint32_t k2 = k0 ^ k1 ^ 0x1BD11BDAu;
#define TFR(r) { x0 += x1; x1 = (x1 << (r)) | (x1 >> (32 - (r))); x1 ^= x0; }
  x0 += k0; x1 += k1;
  TFR(13) TFR(15) TFR(26) TFR(6)
  x0 += k1; x1 += k2 + 1u;
  TFR(17) TFR(29) TFR(16) TFR(24)
  x0 += k2; x1 += k0 + 2u;
  TFR(13) TFR(15) TFR(26) TFR(6)
  x0 += k0; x1 += k1 + 3u;
  TFR(17) TFR(29) TFR(16) TFR(24)
  x0 += k1; x1 += k2 + 4u;
  TFR(13) TFR(15) TFR(26) TFR(6)
  x0 += k2; x1 += k0 + 5u;
#undef TFR
  o0 = x0; o1 = x1;
}

// ---- fast f64 exp (|x| <= ~60; rel err ~1e-16) ----------------------------
__device__ __forceinline__ double exp64(double x) {
  double t = x * 1.4426950408889634074;
  double n = rint(t);
  double r = fma(-n, 6.93147180369123816490e-01, x);
  r = fma(-n, 1.90821492927058770002e-10, r);
  double p = 1.6059043836821613e-10;        // 1/13!
  p = fma(p, r, 2.0876756987868099e-9);
  p = fma(p, r, 2.5052108385441720e-8);
  p = fma(p, r, 2.7557319223985888e-7);
  p = fma(p, r, 2.7557319223985893e-6);
  p = fma(p, r, 2.4801587301587302e-5);
  p = fma(p, r, 1.9841269841269841e-4);
  p = fma(p, r, 1.3888888888888889e-3);
  p = fma(p, r, 8.3333333333333332e-3);
  p = fma(p, r, 4.1666666666666664e-2);
  p = fma(p, r, 1.6666666666666666e-1);
  p = fma(p, r, 0.5);
  p = fma(p, r, 1.0);
  p = fma(p, r, 1.0);
  long long ni = (long long)n;
  double sc = __longlong_as_double((1023LL + ni) << 52);
  return p * sc;
}

// ---- fast f64 log (normal x > 0; abs err ~1e-15) --------------------------
__device__ __forceinline__ double log64(double x) {
  long long b = __double_as_longlong(x);
  long long e = ((b >> 52) & 0x7FF) - 1023;
  double m = __longlong_as_double((b & 0x000FFFFFFFFFFFFFLL) |
                                  0x3FF0000000000000LL);
  if (m > 1.4142135623730951) { m *= 0.5; e += 1; }
  double z = (m - 1.0) / (m + 1.0);
  double z2 = z * z;
  double s = 1.0 / 21.0;
  s = fma(s, z2, 1.0 / 19.0);
  s = fma(s, z2, 1.0 / 17.0);
  s = fma(s, z2, 1.0 / 15.0);
  s = fma(s, z2, 1.0 / 13.0);
  s = fma(s, z2, 1.0 / 11.0);
  s = fma(s, z2, 1.0 / 9.0);
  s = fma(s, z2, 1.0 / 7.0);
  s = fma(s, z2, 1.0 / 5.0);
  s = fma(s, z2, 1.0 / 3.0);
  s = fma(s, z2, 1.0);
  double lm = 2.0 * z * s;
  return fma((double)e, 0.6931471805599453094, lm);
}

__device__ __forceinline__ double tanh64(double x) {
  double t = exp64(2.0 * x);
  return 1.0 - 2.0 / (t + 1.0);
}

// ---- gumbel: partitionable threefry bits -> exact f32 uniform -> f64 ------
__device__ __forceinline__ double gumbel64(uint32_t k0, uint32_t k1,
                                           uint32_t e) {
  uint32_t o0, o1;
  tf2x32(k0, k1, 0u, e, o0, o1);
  uint32_t bits = o0 ^ o1;
  float uf = __uint_as_float((bits >> 9) | 0x3f800000u) - 1.0f;  // exact
  double u = (double)uf;
  if (u == 0.0) u = 1.1754943508222875e-38;
  return -log64(-log64(u));
}

// ---- prep: WHH quads (f64), PX = emb @ W_ih^T quads, zero gacc ------------
__global__ void ctrl_prep(const float* __restrict__ emb,
                          const float* __restrict__ W_ih,
                          const float* __restrict__ W_hh,
                          double* __restrict__ ws) {
  int gid = blockIdx.x * blockDim.x + threadIdx.x;
  if (gid < HID * NCOL) {
    int k = gid / NCOL, j = gid % NCOL;
    double* dst = ws + WHH_D + 4 * gid;
    double v0 = 0, v1 = 0, v2 = 0, v3 = 0;
    if (j < HID) {
      v0 = (double)W_hh[(0 * HID + j) * HID + k];
      v1 = (double)W_hh[(1 * HID + j) * HID + k];
      v2 = (double)W_hh[(2 * HID + j) * HID + k];
      v3 = (double)W_hh[(3 * HID + j) * HID + k];
    }
    dst[0] = v0; dst[1] = v1; dst[2] = v2; dst[3] = v3;
  } else if (gid < HID * NCOL + 25 * NCOL) {
    int t = gid - HID * NCOL;
    int a = t / NCOL, j = t % NCOL;
    double* dst = ws + PX_D + 4 * t;
    double v[4] = {0.0, 0.0, 0.0, 0.0};
    if (j < HID && a < 24) {
#pragma unroll
      for (int g = 0; g < 4; ++g) {
        const float* wr = W_ih + (g * HID + j) * EMB;
        const float* ev = emb + a * EMB;
        double acc = 0.0;
        for (int e = 0; e < EMB; ++e)
          acc = fma((double)wr[e], (double)ev[e], acc);
        v[g] = acc;
      }
    }
    dst[0] = v[0]; dst[1] = v[1]; dst[2] = v[2]; dst[3] = v[3];
  }
  if (gid < NOPS + NMAGS) ws[GACC_D + gid] = 0.0;
}

// ---- head matvec + z + gumbel ---------------------------------------------
template <int K>
__device__ __forceinline__ void head_phase(
    int tid, int base_b, const float* __restrict__ Wh,
    const float* __restrict__ bh, uint32_t key0, uint32_t key1,
    const double (*hb)[ROWS], double (*zb)[16], double (*gb)[16]) {
  if (tid < ROWS * K) {
    int r = tid / K, c = tid - r * K;
    const float* wrow = Wh + c * HID;
    double acc = 0.0;
#pragma unroll 4
    for (int k = 0; k < HID; ++k)
      acc = fma((double)wrow[k], hb[k][r], acc);
    zb[r][c] = 2.5 * tanh64(acc + (double)bh[c]);
    gb[r][c] = gumbel64(key0, key1, (uint32_t)((base_b + r) * K + c));
  }
}

// ---- per-row softmax / entropy / gumbel-argmax ----------------------------
template <int K>
__device__ __forceinline__ void sample_phase(
    int r, int base_b, int sidx, int eoff, double (*zb)[16], double (*gb)[16],
    double (*pb)[16], int* act, float* __restrict__ out, double& lp_run,
    double& en_run) {
  double m = zb[r][0];
#pragma unroll
  for (int k = 1; k < K; ++k) m = fmax(m, zb[r][k]);
  double s = 0.0;
#pragma unroll
  for (int k = 0; k < K; ++k) s += exp64(zb[r][k] - m);
  double ls = log64(s);
  double ent = 0.0, best = 0.0, sel = 0.0;
  int bi = 0;
#pragma unroll
  for (int k = 0; k < K; ++k) {
    double zk = zb[r][k];
    double lp = zk - m - ls;
    double pr = exp64(lp);
    pb[r][k] = pr;
    ent = fma(lp, pr, ent);
    double sc = gb[r][k] + zk;           // argmax(z + gumbel), first-max tie
    if (k == 0 || sc > best) { best = sc; bi = k; sel = lp; }
  }
  out[(size_t)(base_b + r) * TOT + sidx] = (float)bi;
  lp_run += sel;
  en_run += -ent;
  act[r] = bi + eoff;
}

// ---- main -----------------------------------------------------------------
__global__ __launch_bounds__(NT, 4)
void ctrl_main(const float* __restrict__ b_ih, const float* __restrict__ b_hh,
               const float* __restrict__ W_op, const float* __restrict__ b_op,
               const float* __restrict__ W_mag, const float* __restrict__ b_mag,
               const double* __restrict__ ws, double* __restrict__ gacc,
               double* __restrict__ lpp, double* __restrict__ enp,
               float* __restrict__ out, KeyArr keys) {
  __shared__ double hbuf[2][HID][ROWS];       // double-buffered h, k-major
  __shared__ double zb[ROWS][16], gb[ROWS][16], pb[ROWS][16];
  __shared__ int act[ROWS];

  const int tid = threadIdx.x;
  const int jq = tid % NCOL;
  const int rb = (tid / NCOL) * 8;
  const int bid = blockIdx.x;
  const int q = bid >> 8;                     // 5 q x 256 row-groups
  const int base_b = (bid & 255) * ROWS;
  const bool on = (jq < HID);

  for (int t = tid; t < HID * ROWS; t += NT) (&hbuf[0][0][0])[t] = 0.0;
  if (tid < ROWS) act[tid] = 24;              // step-0 input: zero vector

  const double* WHH = ws + WHH_D;
  const double* PX = ws + PX_D;

  double bsi = 0, bsf = 0, bsg = 0, bso = 0;
  if (on) {
    bsi = (double)b_ih[jq]       + (double)b_hh[jq];
    bsf = (double)b_ih[100 + jq] + (double)b_hh[100 + jq];
    bsg = (double)b_ih[200 + jq] + (double)b_hh[200 + jq];
    bso = (double)b_ih[300 + jq] + (double)b_hh[300 + jq];
  }

  double creg[8];
#pragma unroll
  for (int r = 0; r < 8; ++r) creg[r] = 0.0;
  double lp_run = 0.0, en_run = 0.0, op_run = 0.0, mag_run = 0.0;
  int cur = 0;
  __syncthreads();

  for (int js = 0; js < NSTEP; ++js) {
    const int nxt = cur ^ 1;
    // ---- P1: gates = PX[act] + h @ WHH; nonlinearity; write h -> hbuf[nxt]
    double ai[8], af[8], ag[8], ao[8];
#pragma unroll
    for (int r = 0; r < 8; ++r) {
      const double* px = PX + 4 * ((size_t)act[rb + r] * NCOL + jq);
      ai[r] = px[0]; af[r] = px[1]; ag[r] = px[2]; ao[r] = px[3];
    }
    const double* hb = &hbuf[cur][0][0] + rb;
#pragma unroll 2
    for (int k = 0; k < HID; ++k) {
      const double* w = WHH + 4 * (k * NCOL + jq);
      double wi = w[0], wf = w[1], wg = w[2], wo = w[3];
      const double* hrow = hb + k * ROWS;
      double2 ha = *(const double2*)(hrow + 0);
      double2 hbb = *(const double2*)(hrow + 2);
      double2 hc = *(const double2*)(hrow + 4);
      double2 hd = *(const double2*)(hrow + 6);
      double hv[8] = {ha.x, ha.y, hbb.x, hbb.y, hc.x, hc.y, hd.x, hd.y};
#pragma unroll
      for (int r = 0; r < 8; ++r) {
        ai[r] = fma(wi, hv[r], ai[r]);
        af[r] = fma(wf, hv[r], af[r]);
        ag[r] = fma(wg, hv[r], ag[r]);
        ao[r] = fma(wo, hv[r], ao[r]);
      }
    }
    if (on) {
      double hw[8];
#pragma unroll
      for (int r = 0; r < 8; ++r) {
        double gi = ai[r] + bsi, gf = af[r] + bsf;
        double gg = ag[r] + bsg, go = ao[r] + bso;
        double ef = exp64(-gf);
        double ei = exp64(-gi);
        double eg = exp64(2.0 * gg);
        double eo = exp64(-go);
        // c2 = sigmoid(f)*c + sigmoid(i)*tanh(g)
        double c2 = creg[r] / (1.0 + ef) +
                    (eg - 1.0) / ((eg + 1.0) * (1.0 + ei));
        creg[r] = c2;
        double ec = exp64(2.0 * c2);
        hw[r] = (ec - 1.0) / ((ec + 1.0) * (1.0 + eo));  // sigmoid(o)*tanh(c2)
      }
      double* dst = &hbuf[nxt][jq][rb];
      ((double2*)dst)[0] = make_double2(hw[0], hw[1]);
      ((double2*)dst)[1] = make_double2(hw[2], hw[3]);
      ((double2*)dst)[2] = make_double2(hw[4], hw[5]);
      ((double2*)dst)[3] = make_double2(hw[6], hw[7]);
    }
    __syncthreads();                         // bar1: h visible, reads done

    const int sidx = q * NSTEP + js;
    const uint32_t key0 = keys.k[2 * sidx], key1 = keys.k[2 * sidx + 1];
    if (js & 1)
      head_phase<NMAGS>(tid, base_b, W_mag, b_mag, key0, key1, hbuf[nxt], zb, gb);
    else
      head_phase<NOPS>(tid, base_b, W_op, b_op, key0, key1, hbuf[nxt], zb, gb);
    __syncthreads();                         // bar2: zb/gb visible

    if (tid < ROWS) {
      if (js & 1)
        sample_phase<NMAGS>(tid, base_b, sidx, NOPS, zb, gb, pb, act, out,
                            lp_run, en_run);
      else
        sample_phase<NOPS>(tid, base_b, sidx, 0, zb, gb, pb, act, out,
                           lp_run, en_run);
    }
    __syncthreads();                         // bar3: pb/act visible

    if (js & 1) {
      if (tid < NMAGS) {
        double cs = 0.0;
        for (int r = 0; r < ROWS; ++r) cs += pb[r][tid];
        mag_run += cs;
      }
    } else {
      if (tid < NOPS) {
        double cs = 0.0;
        for (int r = 0; r < ROWS; ++r) cs += pb[r][tid];
        op_run += cs;
      }
    }
    cur = nxt;
  }

  if (tid < ROWS) {
    lpp[q * BTOT + base_b + tid] = lp_run;
    enp[q * BTOT + base_b + tid] = en_run;
  }
  if (tid < NOPS) atomicAdd(&gacc[tid], op_run);
  if (tid < NMAGS) atomicAdd(&gacc[NOPS + tid], mag_run);
}

// ---- finish: q-ordered partial sums + prob means --------------------------
__global__ void ctrl_fin(const double* __restrict__ ws,
                         float* __restrict__ out) {
  int gid = blockIdx.x * blockDim.x + threadIdx.x;
  if (gid < BTOT) {
    const double* lpp = ws + LPP_D;
    const double* enp = ws + ENP_D;
    double s1 = 0.0, s2 = 0.0;
#pragma unroll
    for (int qq = 0; qq < QC; ++qq) {
      s1 += lpp[qq * BTOT + gid];
      s2 += enp[qq * BTOT + gid];
    }
    out[OUT_LPS + gid] = (float)s1;
    out[OUT_ENTS + gid] = (float)s2;
  } else if (gid < BTOT + NOPS + NMAGS) {
    int t = gid - BTOT;
    double v = ws[GACC_D + t] / 163840.0;
    if (t < NOPS) out[OUT_OPM + t] = (float)v;
    else out[OUT_MAGM + (t - NOPS)] = (float)v;
  }
}

extern "C" void kernel_launch(void* const* d_in, const int* in_sizes, int n_in,
                              void* d_out, int out_size, void* d_ws,
                              size_t ws_size, hipStream_t stream) {
  const float* emb   = (const float*)d_in[0];
  const float* W_ih  = (const float*)d_in[1];
  const float* W_hh  = (const float*)d_in[2];
  const float* b_ih  = (const float*)d_in[3];
  const float* b_hh  = (const float*)d_in[4];
  const float* W_op  = (const float*)d_in[5];
  const float* b_op  = (const float*)d_in[6];
  const float* W_mag = (const float*)d_in[7];
  const float* b_mag = (const float*)d_in[8];
  float* out = (float*)d_out;
  double* ws = (double*)d_ws;

  // fold_in(key(42), s) = threefry2x32(key=(0,42), count=(0,s))
  KeyArr keys;
  for (int s = 0; s < TOT; ++s) {
    uint32_t o0, o1;
    tf2x32(0u, 42u, 0u, (uint32_t)s, o0, o1);
    keys.k[2 * s] = o0;
    keys.k[2 * s + 1] = o1;
  }

  ctrl_prep<<<dim3((HID * NCOL + 25 * NCOL + 255) / 256), dim3(256), 0,
              stream>>>(emb, W_ih, W_hh, ws);
  ctrl_main<<<dim3(NBLK), dim3(NT), 0, stream>>>(
      b_ih, b_hh, W_op, b_op, W_mag, b_mag, ws, ws + GACC_D, ws + LPP_D,
      ws + ENP_D, out, keys);
  ctrl_fin<<<dim3((BTOT + NOPS + NMAGS + 255) / 256), dim3(256), 0, stream>>>(
      ws, out);
}